// Round 2
// baseline (660.849 us; speedup 1.0000x reference)
//
#include <hip/hip_runtime.h>

typedef _Float16 half8 __attribute__((ext_vector_type(8)));
typedef _Float16 half4 __attribute__((ext_vector_type(4)));
typedef float f32x4 __attribute__((ext_vector_type(4)));

#define AS1 __attribute__((address_space(1)))
#define AS3 __attribute__((address_space(3)))

// ---------------- fp32 -> fp16 bulk convert ----------------
__global__ __launch_bounds__(256) void cvt_kernel(const float* __restrict__ src,
                                                  _Float16* __restrict__ dst, int n4) {
    int i = blockIdx.x * blockDim.x + threadIdx.x;
    int stride = gridDim.x * blockDim.x;
    const float4* s4 = (const float4*)src;
    half4* d4 = (half4*)dst;
    for (; i < n4; i += stride) {
        float4 f = s4[i];
        half4 o;
        o.x = (_Float16)f.x; o.y = (_Float16)f.y; o.z = (_Float16)f.z; o.w = (_Float16)f.w;
        d4[i] = o;
    }
}

// ---------------- weight transpose + convert: W[1024][1024] f32 -> Wt[n][k] fp16 ----------------
__global__ __launch_bounds__(256) void wtrans_kernel(const float* __restrict__ W0, const float* __restrict__ W1,
                                                     const float* __restrict__ W2,
                                                     _Float16* __restrict__ T0, _Float16* __restrict__ T1,
                                                     _Float16* __restrict__ T2) {
    const float* W = blockIdx.z == 0 ? W0 : (blockIdx.z == 1 ? W1 : W2);
    _Float16* T = blockIdx.z == 0 ? T0 : (blockIdx.z == 1 ? T1 : T2);
    __shared__ float tile[32][33];
    int tx = threadIdx.x & 31, tg = threadIdx.x >> 5;  // tg 0..7
    int k0 = blockIdx.y * 32, n0 = blockIdx.x * 32;
#pragma unroll
    for (int i = 0; i < 4; i++) tile[tg + i * 8][tx] = W[(long)(k0 + tg + i * 8) * 1024 + n0 + tx];
    __syncthreads();
#pragma unroll
    for (int i = 0; i < 4; i++) T[(long)(n0 + tg + i * 8) * 1024 + k0 + tx] = (_Float16)tile[tx][tg + i * 8];
}

// ---------------- m97-style GEMM: C[M][N] = A[M][K] * Bt[N][K]^T ----------------
// OUTK: 0 = fp16 row-major store (+bias, *scale)
//       1 = f32 row-major store
//       2 = fp16 store transposed per 2048-row batch: Vt[b][n][t], b=m>>11, t=m&2047
template <int OUTK>
__global__ __launch_bounds__(256) void gemm_bt(const _Float16* __restrict__ A, long bsA, int lda,
                                               const _Float16* __restrict__ Bt, long bsB, int ldb,
                                               void* __restrict__ Cv, long bsC, int ldc,
                                               const float* __restrict__ bias, float scale, int K) {
    __shared__ __align__(16) _Float16 sA[128 * 32];
    __shared__ __align__(16) _Float16 sB[128 * 32];
    const int tid = threadIdx.x;
    const int wv = tid >> 6, lane = tid & 63;
    const int wr = wv >> 1, wc = wv & 1;
    const int quad = lane >> 4, l16 = lane & 15;
    const long zb = blockIdx.z;
    const _Float16* Ab = A + zb * bsA + (long)(blockIdx.y * 128) * lda;
    const _Float16* Bb = Bt + zb * bsB + (long)(blockIdx.x * 128) * ldb;

    f32x4 acc[4][4];
#pragma unroll
    for (int i = 0; i < 4; i++)
#pragma unroll
        for (int j = 0; j < 4; j++) acc[i][j] = {0.f, 0.f, 0.f, 0.f};

    const int srow = lane >> 2;          // 0..15
    const int skoff = (lane & 3) * 8;    // 0,8,16,24
    const int c0 = wv * 2;

    for (int k0 = 0; k0 < K; k0 += 32) {
#pragma unroll
        for (int c = c0; c < c0 + 2; ++c) {
            int row = c * 16 + srow;
            __builtin_amdgcn_global_load_lds((const AS1 void*)(Ab + (long)row * lda + k0 + skoff),
                                             (AS3 void*)(&sA[c * 512]), 16, 0, 0);
            __builtin_amdgcn_global_load_lds((const AS1 void*)(Bb + (long)row * ldb + k0 + skoff),
                                             (AS3 void*)(&sB[c * 512]), 16, 0, 0);
        }
        __syncthreads();
        half8 af[4], bfr[4];
#pragma unroll
        for (int mi = 0; mi < 4; mi++) af[mi] = *(const half8*)&sA[(wr * 64 + mi * 16 + l16) * 32 + quad * 8];
#pragma unroll
        for (int ni = 0; ni < 4; ni++) bfr[ni] = *(const half8*)&sB[(wc * 64 + ni * 16 + l16) * 32 + quad * 8];
#pragma unroll
        for (int mi = 0; mi < 4; mi++)
#pragma unroll
            for (int ni = 0; ni < 4; ni++)
                acc[mi][ni] = __builtin_amdgcn_mfma_f32_16x16x32_f16(af[mi], bfr[ni], acc[mi][ni], 0, 0, 0);
        __syncthreads();
    }

    const int m_base = blockIdx.y * 128 + wr * 64 + quad * 4;
    const int n_base = blockIdx.x * 128 + wc * 64 + l16;
    if (OUTK == 0) {
        _Float16* C = (_Float16*)Cv + zb * bsC;
#pragma unroll
        for (int mi = 0; mi < 4; mi++)
#pragma unroll
            for (int ni = 0; ni < 4; ni++) {
                int n = n_base + ni * 16;
                float bv_ = bias ? bias[n] : 0.f;
#pragma unroll
                for (int r = 0; r < 4; r++) {
                    int m = m_base + mi * 16 + r;
                    C[(long)m * ldc + n] = (_Float16)(acc[mi][ni][r] * scale + bv_);
                }
            }
    } else if (OUTK == 1) {
        float* C = (float*)Cv + zb * bsC;
#pragma unroll
        for (int mi = 0; mi < 4; mi++)
#pragma unroll
            for (int ni = 0; ni < 4; ni++) {
                int n = n_base + ni * 16;
                float bv_ = bias ? bias[n] : 0.f;
#pragma unroll
                for (int r = 0; r < 4; r++) {
                    int m = m_base + mi * 16 + r;
                    C[(long)m * ldc + n] = acc[mi][ni][r] * scale + bv_;
                }
            }
    } else {  // OUTK == 2: Vt[b][n][t]
        _Float16* C = (_Float16*)Cv;
#pragma unroll
        for (int mi = 0; mi < 4; mi++) {
            int m0 = m_base + mi * 16;  // 4 consecutive rows m0..m0+3, same batch (128 | 2048)
            long b = m0 >> 11;
            int t = m0 & 2047;
#pragma unroll
            for (int ni = 0; ni < 4; ni++) {
                int n = n_base + ni * 16;
                float bv_ = bias ? bias[n] : 0.f;
                half4 o;
                o.x = (_Float16)(acc[mi][ni][0] * scale + bv_);
                o.y = (_Float16)(acc[mi][ni][1] * scale + bv_);
                o.z = (_Float16)(acc[mi][ni][2] * scale + bv_);
                o.w = (_Float16)(acc[mi][ni][3] * scale + bv_);
                *(half4*)&C[b * (1024L * 2048) + (long)n * 2048 + t] = o;
            }
        }
    }
}

// ---------------- in-place row softmax on fp16 scores, row length 2048 ----------------
__global__ __launch_bounds__(256) void softmax_kernel(_Float16* __restrict__ S) {
    const long row = blockIdx.x;
    _Float16* p = S + row * 2048;
    half8 raw = ((const half8*)p)[threadIdx.x];
    float v[8];
#pragma unroll
    for (int i = 0; i < 8; i++) v[i] = (float)raw[i];

    float mx = v[0];
#pragma unroll
    for (int i = 1; i < 8; i++) mx = fmaxf(mx, v[i]);
#pragma unroll
    for (int off = 32; off > 0; off >>= 1) mx = fmaxf(mx, __shfl_xor(mx, off, 64));
    __shared__ float redm[4], reds[4];
    int lane = threadIdx.x & 63, w = threadIdx.x >> 6;
    if (lane == 0) redm[w] = mx;
    __syncthreads();
    mx = fmaxf(fmaxf(redm[0], redm[1]), fmaxf(redm[2], redm[3]));

    float e[8], s = 0.f;
#pragma unroll
    for (int i = 0; i < 8; i++) { e[i] = __expf(v[i] - mx); s += e[i]; }
#pragma unroll
    for (int off = 32; off > 0; off >>= 1) s += __shfl_xor(s, off, 64);
    if (lane == 0) reds[w] = s;
    __syncthreads();
    s = reds[0] + reds[1] + reds[2] + reds[3];
    float inv = 1.0f / s;

    half8 o;
#pragma unroll
    for (int i = 0; i < 8; i++) o[i] = (_Float16)(e[i] * inv);
    ((half8*)p)[threadIdx.x] = o;
}

extern "C" void kernel_launch(void* const* d_in, const int* in_sizes, int n_in,
                              void* d_out, int out_size, void* d_ws, size_t ws_size,
                              hipStream_t stream) {
    const float* H  = (const float*)d_in[0];   // [8,2048,1024]
    const float* E  = (const float*)d_in[1];   // [8,2048,1024]
    const float* Wq = (const float*)d_in[2];
    const float* bq = (const float*)d_in[3];
    const float* Wk = (const float*)d_in[4];
    const float* bk = (const float*)d_in[5];
    const float* Wv = (const float*)d_in[6];
    const float* bv = (const float*)d_in[7];
    float* out = (float*)d_out;

    char* ws = (char*)d_ws;
    _Float16* Hh  = (_Float16*)(ws + 0L);
    _Float16* Eh  = (_Float16*)(ws + 33554432L);
    _Float16* WqT = (_Float16*)(ws + 67108864L);
    _Float16* WkT = (_Float16*)(ws + 69206016L);
    _Float16* WvT = (_Float16*)(ws + 71303168L);
    _Float16* Qh  = (_Float16*)(ws + 73400320L);
    _Float16* Kh  = (_Float16*)(ws + 106954752L);
    _Float16* Vt  = (_Float16*)(ws + 140509184L);
    _Float16* S   = (_Float16*)(ws + 174063616L);  // ends at 241172480

    // 1) fp32 -> fp16 activations
    cvt_kernel<<<2048, 256, 0, stream>>>(H, Hh, 16384 * 1024 / 4);
    cvt_kernel<<<2048, 256, 0, stream>>>(E, Eh, 16384 * 1024 / 4);
    // 2) weight transpose+convert
    wtrans_kernel<<<dim3(32, 32, 3), 256, 0, stream>>>(Wq, Wk, Wv, WqT, WkT, WvT);
    // 3) projections: M=16384, N=1024, K=1024
    gemm_bt<0><<<dim3(8, 128, 1), 256, 0, stream>>>(Hh, 0, 1024, WqT, 0, 1024,
                                                    (void*)Qh, 0, 1024, bq, 1.f, 1024);
    gemm_bt<0><<<dim3(8, 128, 1), 256, 0, stream>>>(Eh, 0, 1024, WkT, 0, 1024,
                                                    (void*)Kh, 0, 1024, bk, 1.f, 1024);
    gemm_bt<2><<<dim3(8, 128, 1), 256, 0, stream>>>(Eh, 0, 1024, WvT, 0, 1024,
                                                    (void*)Vt, 0, 1024, bv, 1.f, 1024);
    // 4) S = Q K^T * 0.125  (batched, M=N=2048, K=1024)
    gemm_bt<0><<<dim3(16, 16, 8), 256, 0, stream>>>(Qh, 2048L * 1024, 1024, Kh,
                                                    2048L * 1024, 1024, (void*)S, 2048L * 2048, 2048, nullptr,
                                                    0.125f, 1024);
    // 5) in-place softmax over rows
    softmax_kernel<<<16384, 256, 0, stream>>>(S);
    // 6) O = P V  (batched, M=2048, N=1024, K=2048), fp32 out
    gemm_bt<1><<<dim3(8, 16, 8), 256, 0, stream>>>(S, 2048L * 2048, 2048, Vt,
                                                   1024L * 2048, 2048, (void*)out, 2048L * 1024, 1024, nullptr,
                                                   1.f, 2048);
    (void)in_sizes; (void)n_in; (void)out_size; (void)ws_size;
}

// Round 3
// 534.659 us; speedup vs baseline: 1.2360x; 1.2360x over previous
//
#include <hip/hip_runtime.h>

typedef _Float16 half8 __attribute__((ext_vector_type(8)));
typedef _Float16 half4 __attribute__((ext_vector_type(4)));
typedef float f32x4 __attribute__((ext_vector_type(4)));

#define AS1 __attribute__((address_space(1)))
#define AS3 __attribute__((address_space(3)))

// ---------------- fp32 -> fp16 bulk convert (H and E in one dispatch) ----------------
__global__ __launch_bounds__(256) void cvt2_kernel(const float* __restrict__ H, const float* __restrict__ E,
                                                   _Float16* __restrict__ Hh, _Float16* __restrict__ Eh, int n4) {
    const float4* s4 = (const float4*)(blockIdx.z ? E : H);
    half4* d4 = (half4*)(blockIdx.z ? Eh : Hh);
    int i = blockIdx.x * blockDim.x + threadIdx.x;
    int stride = gridDim.x * blockDim.x;
    for (; i < n4; i += stride) {
        float4 f = s4[i];
        half4 o;
        o.x = (_Float16)f.x; o.y = (_Float16)f.y; o.z = (_Float16)f.z; o.w = (_Float16)f.w;
        d4[i] = o;
    }
}

// ---------------- weight transpose + convert: W[1024][1024] f32 -> Wt[n][k] fp16 ----------------
__global__ __launch_bounds__(256) void wtrans_kernel(const float* __restrict__ W0, const float* __restrict__ W1,
                                                     const float* __restrict__ W2,
                                                     _Float16* __restrict__ T0, _Float16* __restrict__ T1,
                                                     _Float16* __restrict__ T2) {
    const float* W = blockIdx.z == 0 ? W0 : (blockIdx.z == 1 ? W1 : W2);
    _Float16* T = blockIdx.z == 0 ? T0 : (blockIdx.z == 1 ? T1 : T2);
    __shared__ float tile[32][33];
    int tx = threadIdx.x & 31, tg = threadIdx.x >> 5;  // tg 0..7
    int k0 = blockIdx.y * 32, n0 = blockIdx.x * 32;
#pragma unroll
    for (int i = 0; i < 4; i++) tile[tg + i * 8][tx] = W[(long)(k0 + tg + i * 8) * 1024 + n0 + tx];
    __syncthreads();
#pragma unroll
    for (int i = 0; i < 4; i++) T[(long)(n0 + tg + i * 8) * 1024 + k0 + tx] = (_Float16)tile[tx][tg + i * 8];
}

// ---------------- shared GEMM core: acc += A[128][K] * Bt[128][K]^T, XOR-swizzled LDS ----------------
// LDS tile: 128 rows x 32 k (64 B/row, four 16-B chunks). Logical chunk g of row r lives at
// physical chunk g ^ ((r>>1)&3) -> fragment reads hit 8 distinct banks (2-way, free) instead of 2 (8-way).
__device__ __forceinline__ void gemm_core(const _Float16* __restrict__ Ab, int lda,
                                          const _Float16* __restrict__ Bb, int ldb, int K,
                                          _Float16* sA, _Float16* sB, f32x4 acc[4][4]) {
    const int tid = threadIdx.x;
    const int wv = tid >> 6, lane = tid & 63;
    const int wr = wv >> 1, wc = wv & 1;
    const int quad = lane >> 4, l16 = lane & 15;
    const int srow = lane >> 2;                    // staging row within 16-row group
    const int g = ((lane & 3) ^ ((srow >> 1) & 3)) * 8;   // swizzled source chunk (elements)
    const int rc = (quad ^ ((l16 >> 1) & 3)) * 8;         // swizzled fragment chunk (elements)
    const int c0 = wv * 2;

    for (int k0 = 0; k0 < K; k0 += 32) {
#pragma unroll
        for (int c = c0; c < c0 + 2; ++c) {
            int row = c * 16 + srow;
            __builtin_amdgcn_global_load_lds((const AS1 void*)(Ab + (long)row * lda + k0 + g),
                                             (AS3 void*)(&sA[c * 512]), 16, 0, 0);
            __builtin_amdgcn_global_load_lds((const AS1 void*)(Bb + (long)row * ldb + k0 + g),
                                             (AS3 void*)(&sB[c * 512]), 16, 0, 0);
        }
        __syncthreads();
        half8 af[4], bfr[4];
#pragma unroll
        for (int mi = 0; mi < 4; mi++) af[mi] = *(const half8*)&sA[(wr * 64 + mi * 16 + l16) * 32 + rc];
#pragma unroll
        for (int ni = 0; ni < 4; ni++) bfr[ni] = *(const half8*)&sB[(wc * 64 + ni * 16 + l16) * 32 + rc];
#pragma unroll
        for (int mi = 0; mi < 4; mi++)
#pragma unroll
            for (int ni = 0; ni < 4; ni++)
                acc[mi][ni] = __builtin_amdgcn_mfma_f32_16x16x32_f16(af[mi], bfr[ni], acc[mi][ni], 0, 0, 0);
        __syncthreads();
    }
}

// ---------------- merged QKV projection: grid (8, 128, 3) ----------------
struct QkvParams {
    const _Float16 *Hh, *Eh, *WqT, *WkT, *WvT;
    const float *bq, *bk, *bv;
    _Float16 *Qh, *Kh, *Vt;
};

__global__ __launch_bounds__(256, 4) void qkv_kernel(QkvParams p) {
    __shared__ __align__(16) _Float16 sA[128 * 32];
    __shared__ __align__(16) _Float16 sB[128 * 32];
    const int z = blockIdx.z;
    const _Float16* A  = (z == 0) ? p.Hh : p.Eh;
    const _Float16* Bt = (z == 0) ? p.WqT : (z == 1 ? p.WkT : p.WvT);
    const float* bias  = (z == 0) ? p.bq : (z == 1 ? p.bk : p.bv);
    const _Float16* Ab = A + (long)(blockIdx.y * 128) * 1024;
    const _Float16* Bb = Bt + (long)(blockIdx.x * 128) * 1024;

    f32x4 acc[4][4];
#pragma unroll
    for (int i = 0; i < 4; i++)
#pragma unroll
        for (int j = 0; j < 4; j++) acc[i][j] = {0.f, 0.f, 0.f, 0.f};
    gemm_core(Ab, 1024, Bb, 1024, 1024, sA, sB, acc);

    const int wv = threadIdx.x >> 6, lane = threadIdx.x & 63;
    const int wr = wv >> 1, wc = wv & 1;
    const int quad = lane >> 4, l16 = lane & 15;
    const int m_base = blockIdx.y * 128 + wr * 64 + quad * 4;
    const int n_base = blockIdx.x * 128 + wc * 64 + l16;

    if (z < 2) {
        _Float16* C = (z == 0) ? p.Qh : p.Kh;
#pragma unroll
        for (int mi = 0; mi < 4; mi++)
#pragma unroll
            for (int ni = 0; ni < 4; ni++) {
                int n = n_base + ni * 16;
                float bv_ = bias[n];
#pragma unroll
                for (int r = 0; r < 4; r++)
                    C[(long)(m_base + mi * 16 + r) * 1024 + n] = (_Float16)(acc[mi][ni][r] + bv_);
            }
    } else {  // V: store transposed per batch: Vt[b][n][t]
        _Float16* C = p.Vt;
#pragma unroll
        for (int mi = 0; mi < 4; mi++) {
            int m0 = m_base + mi * 16;
            long b = m0 >> 11;
            int t = m0 & 2047;
#pragma unroll
            for (int ni = 0; ni < 4; ni++) {
                int n = n_base + ni * 16;
                float bv_ = bias[n];
                half4 o;
                o.x = (_Float16)(acc[mi][ni][0] + bv_);
                o.y = (_Float16)(acc[mi][ni][1] + bv_);
                o.z = (_Float16)(acc[mi][ni][2] + bv_);
                o.w = (_Float16)(acc[mi][ni][3] + bv_);
                *(half4*)&C[b * (1024L * 2048) + (long)n * 2048 + t] = o;
            }
        }
    }
}

// ---------------- batched GEMM: OUTK 0 = fp16 store (*scale), 1 = f32 store ----------------
template <int OUTK>
__global__ __launch_bounds__(256, 4) void gemm_bt(const _Float16* __restrict__ A, long bsA, int lda,
                                                  const _Float16* __restrict__ Bt, long bsB, int ldb,
                                                  void* __restrict__ Cv, long bsC, int ldc,
                                                  float scale, int K) {
    __shared__ __align__(16) _Float16 sA[128 * 32];
    __shared__ __align__(16) _Float16 sB[128 * 32];
    const long zb = blockIdx.z;
    const _Float16* Ab = A + zb * bsA + (long)(blockIdx.y * 128) * lda;
    const _Float16* Bb = Bt + zb * bsB + (long)(blockIdx.x * 128) * ldb;

    f32x4 acc[4][4];
#pragma unroll
    for (int i = 0; i < 4; i++)
#pragma unroll
        for (int j = 0; j < 4; j++) acc[i][j] = {0.f, 0.f, 0.f, 0.f};
    gemm_core(Ab, lda, Bb, ldb, K, sA, sB, acc);

    const int wv = threadIdx.x >> 6, lane = threadIdx.x & 63;
    const int wr = wv >> 1, wc = wv & 1;
    const int quad = lane >> 4, l16 = lane & 15;
    const int m_base = blockIdx.y * 128 + wr * 64 + quad * 4;
    const int n_base = blockIdx.x * 128 + wc * 64 + l16;

    if (OUTK == 0) {
        _Float16* C = (_Float16*)Cv + zb * bsC;
#pragma unroll
        for (int mi = 0; mi < 4; mi++)
#pragma unroll
            for (int ni = 0; ni < 4; ni++) {
                int n = n_base + ni * 16;
#pragma unroll
                for (int r = 0; r < 4; r++)
                    C[(long)(m_base + mi * 16 + r) * ldc + n] = (_Float16)(acc[mi][ni][r] * scale);
            }
    } else {
        float* C = (float*)Cv + zb * bsC;
#pragma unroll
        for (int mi = 0; mi < 4; mi++)
#pragma unroll
            for (int ni = 0; ni < 4; ni++) {
                int n = n_base + ni * 16;
#pragma unroll
                for (int r = 0; r < 4; r++)
                    C[(long)(m_base + mi * 16 + r) * ldc + n] = acc[mi][ni][r];
            }
    }
}

// ---------------- in-place row softmax on fp16 scores, row length 2048 ----------------
__global__ __launch_bounds__(256) void softmax_kernel(_Float16* __restrict__ S) {
    const long row = blockIdx.x;
    _Float16* p = S + row * 2048;
    half8 raw = ((const half8*)p)[threadIdx.x];
    float v[8];
#pragma unroll
    for (int i = 0; i < 8; i++) v[i] = (float)raw[i];

    float mx = v[0];
#pragma unroll
    for (int i = 1; i < 8; i++) mx = fmaxf(mx, v[i]);
#pragma unroll
    for (int off = 32; off > 0; off >>= 1) mx = fmaxf(mx, __shfl_xor(mx, off, 64));
    __shared__ float redm[4], reds[4];
    int lane = threadIdx.x & 63, w = threadIdx.x >> 6;
    if (lane == 0) redm[w] = mx;
    __syncthreads();
    mx = fmaxf(fmaxf(redm[0], redm[1]), fmaxf(redm[2], redm[3]));

    float e[8], s = 0.f;
#pragma unroll
    for (int i = 0; i < 8; i++) { e[i] = __expf(v[i] - mx); s += e[i]; }
#pragma unroll
    for (int off = 32; off > 0; off >>= 1) s += __shfl_xor(s, off, 64);
    if (lane == 0) reds[w] = s;
    __syncthreads();
    s = reds[0] + reds[1] + reds[2] + reds[3];
    float inv = 1.0f / s;

    half8 o;
#pragma unroll
    for (int i = 0; i < 8; i++) o[i] = (_Float16)(e[i] * inv);
    ((half8*)p)[threadIdx.x] = o;
}

extern "C" void kernel_launch(void* const* d_in, const int* in_sizes, int n_in,
                              void* d_out, int out_size, void* d_ws, size_t ws_size,
                              hipStream_t stream) {
    const float* H  = (const float*)d_in[0];
    const float* E  = (const float*)d_in[1];
    const float* Wq = (const float*)d_in[2];
    const float* bq = (const float*)d_in[3];
    const float* Wk = (const float*)d_in[4];
    const float* bk = (const float*)d_in[5];
    const float* Wv = (const float*)d_in[6];
    const float* bv = (const float*)d_in[7];
    float* out = (float*)d_out;

    char* ws = (char*)d_ws;
    _Float16* Hh  = (_Float16*)(ws + 0L);
    _Float16* Eh  = (_Float16*)(ws + 33554432L);
    _Float16* WqT = (_Float16*)(ws + 67108864L);
    _Float16* WkT = (_Float16*)(ws + 69206016L);
    _Float16* WvT = (_Float16*)(ws + 71303168L);
    _Float16* Qh  = (_Float16*)(ws + 73400320L);
    _Float16* Kh  = (_Float16*)(ws + 106954752L);
    _Float16* Vt  = (_Float16*)(ws + 140509184L);
    _Float16* S   = (_Float16*)(ws + 174063616L);  // ends at 241172480

    // 1) fp32 -> fp16 activations (both tensors, one dispatch)
    cvt2_kernel<<<dim3(2048, 1, 2), 256, 0, stream>>>(H, E, Hh, Eh, 16384 * 1024 / 4);
    // 2) weight transpose+convert
    wtrans_kernel<<<dim3(32, 32, 3), 256, 0, stream>>>(Wq, Wk, Wv, WqT, WkT, WvT);
    // 3) merged QKV projections: M=16384, N=1024, K=1024, z selects
    QkvParams qp{Hh, Eh, WqT, WkT, WvT, bq, bk, bv, Qh, Kh, Vt};
    qkv_kernel<<<dim3(8, 128, 3), 256, 0, stream>>>(qp);
    // 4) S = Q K^T * 0.125  (batched, M=N=2048, K=1024)
    gemm_bt<0><<<dim3(16, 16, 8), 256, 0, stream>>>(Qh, 2048L * 1024, 1024, Kh, 2048L * 1024, 1024,
                                                    (void*)S, 2048L * 2048, 2048, 0.125f, 1024);
    // 5) in-place softmax over rows
    softmax_kernel<<<16384, 256, 0, stream>>>(S);
    // 6) O = P V  (batched, M=2048, N=1024, K=2048), fp32 out
    gemm_bt<1><<<dim3(8, 16, 8), 256, 0, stream>>>(S, 2048L * 2048, 2048, Vt, 1024L * 2048, 2048,
                                                   (void*)out, 2048L * 1024, 1024, 1.f, 2048);
    (void)in_sizes; (void)n_in; (void)out_size; (void)ws_size;
}

// Round 4
// 481.808 us; speedup vs baseline: 1.3716x; 1.1097x over previous
//
#include <hip/hip_runtime.h>

typedef _Float16 half8 __attribute__((ext_vector_type(8)));
typedef _Float16 half4 __attribute__((ext_vector_type(4)));
typedef float f32x4 __attribute__((ext_vector_type(4)));

#define AS1 __attribute__((address_space(1)))
#define AS3 __attribute__((address_space(3)))

// ---------------- fp32 -> fp16 bulk convert (H and E in one dispatch) ----------------
__global__ __launch_bounds__(256) void cvt2_kernel(const float* __restrict__ H, const float* __restrict__ E,
                                                   _Float16* __restrict__ Hh, _Float16* __restrict__ Eh, int n4) {
    const float4* s4 = (const float4*)(blockIdx.z ? E : H);
    half4* d4 = (half4*)(blockIdx.z ? Eh : Hh);
    int i = blockIdx.x * blockDim.x + threadIdx.x;
    int stride = gridDim.x * blockDim.x;
    for (; i < n4; i += stride) {
        float4 f = s4[i];
        half4 o;
        o.x = (_Float16)f.x; o.y = (_Float16)f.y; o.z = (_Float16)f.z; o.w = (_Float16)f.w;
        d4[i] = o;
    }
}

// ---------------- weight transpose + convert: W[1024][1024] f32 -> Wt[n][k] fp16 ----------------
__global__ __launch_bounds__(256) void wtrans_kernel(const float* __restrict__ W0, const float* __restrict__ W1,
                                                     const float* __restrict__ W2,
                                                     _Float16* __restrict__ T0, _Float16* __restrict__ T1,
                                                     _Float16* __restrict__ T2) {
    const float* W = blockIdx.z == 0 ? W0 : (blockIdx.z == 1 ? W1 : W2);
    _Float16* T = blockIdx.z == 0 ? T0 : (blockIdx.z == 1 ? T1 : T2);
    __shared__ float tile[32][33];
    int tx = threadIdx.x & 31, tg = threadIdx.x >> 5;  // tg 0..7
    int k0 = blockIdx.y * 32, n0 = blockIdx.x * 32;
#pragma unroll
    for (int i = 0; i < 4; i++) tile[tg + i * 8][tx] = W[(long)(k0 + tg + i * 8) * 1024 + n0 + tx];
    __syncthreads();
#pragma unroll
    for (int i = 0; i < 4; i++) T[(long)(n0 + tg + i * 8) * 1024 + k0 + tx] = (_Float16)tile[tx][tg + i * 8];
}

// ---------------- shared GEMM core: acc += A[128][K] * Bt[128][K]^T, XOR-swizzled LDS ----------------
// LDS tile: 128 rows x 32 k (64 B/row, four 16-B chunks). Logical chunk g of row r lives at
// physical chunk g ^ ((r>>1)&3) -> fragment reads hit 8 distinct banks (2-way, free) instead of 8-way.
__device__ __forceinline__ void gemm_core(const _Float16* __restrict__ Ab, int lda,
                                          const _Float16* __restrict__ Bb, int ldb, int K,
                                          _Float16* sA, _Float16* sB, f32x4 acc[4][4]) {
    const int tid = threadIdx.x;
    const int wv = tid >> 6, lane = tid & 63;
    const int wr = wv >> 1, wc = wv & 1;
    const int quad = lane >> 4, l16 = lane & 15;
    const int srow = lane >> 2;                    // staging row within 16-row group
    const int g = ((lane & 3) ^ ((srow >> 1) & 3)) * 8;   // swizzled source chunk (elements)
    const int rc = (quad ^ ((l16 >> 1) & 3)) * 8;         // swizzled fragment chunk (elements)
    const int c0 = wv * 2;

    for (int k0 = 0; k0 < K; k0 += 32) {
#pragma unroll
        for (int c = c0; c < c0 + 2; ++c) {
            int row = c * 16 + srow;
            __builtin_amdgcn_global_load_lds((const AS1 void*)(Ab + (long)row * lda + k0 + g),
                                             (AS3 void*)(&sA[c * 512]), 16, 0, 0);
            __builtin_amdgcn_global_load_lds((const AS1 void*)(Bb + (long)row * ldb + k0 + g),
                                             (AS3 void*)(&sB[c * 512]), 16, 0, 0);
        }
        __syncthreads();
        half8 af[4], bfr[4];
#pragma unroll
        for (int mi = 0; mi < 4; mi++) af[mi] = *(const half8*)&sA[(wr * 64 + mi * 16 + l16) * 32 + rc];
#pragma unroll
        for (int ni = 0; ni < 4; ni++) bfr[ni] = *(const half8*)&sB[(wc * 64 + ni * 16 + l16) * 32 + rc];
#pragma unroll
        for (int mi = 0; mi < 4; mi++)
#pragma unroll
            for (int ni = 0; ni < 4; ni++)
                acc[mi][ni] = __builtin_amdgcn_mfma_f32_16x16x32_f16(af[mi], bfr[ni], acc[mi][ni], 0, 0, 0);
        __syncthreads();
    }
}

// ---------------- merged QKV projection: 1-D grid 3072, XCD-swizzled (xcd = y%8) ----------------
struct QkvParams {
    const _Float16 *Hh, *Eh, *WqT, *WkT, *WvT;
    const float *bq, *bk, *bv;
    _Float16 *Qh, *Kh, *Vt;
};

__global__ __launch_bounds__(256, 4) void qkv_kernel(QkvParams p) {
    __shared__ __align__(16) _Float16 sA[128 * 32];
    __shared__ __align__(16) _Float16 sB[128 * 32];
    // HW maps workgroup b to XCD b%8 (round-robin). Keep all 8 x-tiles of one A-row-tile
    // on the same XCD so its L2 serves the reuse.
    const int b = blockIdx.x;             // 0..3071
    const int xcd = b & 7, s = b >> 3;    // s: 0..383
    const int z = s >> 7;                 // 0..2
    const int r = s & 127;
    const int by = xcd + ((r >> 3) << 3); // 0..127, by%8 == xcd
    const int bx = r & 7;                 // 0..7

    const _Float16* A  = (z == 0) ? p.Hh : p.Eh;
    const _Float16* Bt = (z == 0) ? p.WqT : (z == 1 ? p.WkT : p.WvT);
    const float* bias  = (z == 0) ? p.bq : (z == 1 ? p.bk : p.bv);
    const _Float16* Ab = A + (long)(by * 128) * 1024;
    const _Float16* Bb = Bt + (long)(bx * 128) * 1024;

    f32x4 acc[4][4];
#pragma unroll
    for (int i = 0; i < 4; i++)
#pragma unroll
        for (int j = 0; j < 4; j++) acc[i][j] = {0.f, 0.f, 0.f, 0.f};
    gemm_core(Ab, 1024, Bb, 1024, 1024, sA, sB, acc);

    const int wv = threadIdx.x >> 6, lane = threadIdx.x & 63;
    const int wr = wv >> 1, wc = wv & 1;
    const int quad = lane >> 4, l16 = lane & 15;
    const int m_base = by * 128 + wr * 64 + quad * 4;
    const int n_base = bx * 128 + wc * 64 + l16;

    if (z < 2) {
        _Float16* C = (z == 0) ? p.Qh : p.Kh;
#pragma unroll
        for (int mi = 0; mi < 4; mi++)
#pragma unroll
            for (int ni = 0; ni < 4; ni++) {
                int n = n_base + ni * 16;
                float bv_ = bias[n];
#pragma unroll
                for (int r2 = 0; r2 < 4; r2++)
                    C[(long)(m_base + mi * 16 + r2) * 1024 + n] = (_Float16)(acc[mi][ni][r2] + bv_);
            }
    } else {  // V: store transposed per batch: Vt[b][n][t]
        _Float16* C = p.Vt;
#pragma unroll
        for (int mi = 0; mi < 4; mi++) {
            int m0 = m_base + mi * 16;
            long bb = m0 >> 11;
            int t = m0 & 2047;
#pragma unroll
            for (int ni = 0; ni < 4; ni++) {
                int n = n_base + ni * 16;
                float bv_ = bias[n];
                half4 o;
                o.x = (_Float16)(acc[mi][ni][0] + bv_);
                o.y = (_Float16)(acc[mi][ni][1] + bv_);
                o.z = (_Float16)(acc[mi][ni][2] + bv_);
                o.w = (_Float16)(acc[mi][ni][3] + bv_);
                *(half4*)&C[bb * (1024L * 2048) + (long)n * 2048 + t] = o;
            }
        }
    }
}

// ---------------- batched GEMM, 1-D grid, batch z pinned to XCD z ----------------
// OUTK 0 = fp16 store (*scale), 1 = f32 store. GXLOG = log2(#x-tiles).
template <int OUTK, int GXLOG>
__global__ __launch_bounds__(256, 4) void gemm_bt(const _Float16* __restrict__ A, long bsA, int lda,
                                                  const _Float16* __restrict__ Bt, long bsB, int ldb,
                                                  void* __restrict__ Cv, long bsC, int ldc,
                                                  float scale, int K) {
    __shared__ __align__(16) _Float16 sA[128 * 32];
    __shared__ __align__(16) _Float16 sB[128 * 32];
    const int b = blockIdx.x;
    const long zb = b & 7;                 // batch == XCD
    const int s = b >> 3;
    const int bx = s & ((1 << GXLOG) - 1);
    const int by = s >> GXLOG;

    const _Float16* Ab = A + zb * bsA + (long)(by * 128) * lda;
    const _Float16* Bb = Bt + zb * bsB + (long)(bx * 128) * ldb;

    f32x4 acc[4][4];
#pragma unroll
    for (int i = 0; i < 4; i++)
#pragma unroll
        for (int j = 0; j < 4; j++) acc[i][j] = {0.f, 0.f, 0.f, 0.f};
    gemm_core(Ab, lda, Bb, ldb, K, sA, sB, acc);

    const int wv = threadIdx.x >> 6, lane = threadIdx.x & 63;
    const int wr = wv >> 1, wc = wv & 1;
    const int quad = lane >> 4, l16 = lane & 15;
    const int m_base = by * 128 + wr * 64 + quad * 4;
    const int n_base = bx * 128 + wc * 64 + l16;

    if (OUTK == 0) {
        _Float16* C = (_Float16*)Cv + zb * bsC;
#pragma unroll
        for (int mi = 0; mi < 4; mi++)
#pragma unroll
            for (int ni = 0; ni < 4; ni++) {
                int n = n_base + ni * 16;
#pragma unroll
                for (int r = 0; r < 4; r++)
                    C[(long)(m_base + mi * 16 + r) * ldc + n] = (_Float16)(acc[mi][ni][r] * scale);
            }
    } else {
        float* C = (float*)Cv + zb * bsC;
#pragma unroll
        for (int mi = 0; mi < 4; mi++)
#pragma unroll
            for (int ni = 0; ni < 4; ni++) {
                int n = n_base + ni * 16;
#pragma unroll
                for (int r = 0; r < 4; r++)
                    C[(long)(m_base + mi * 16 + r) * ldc + n] = acc[mi][ni][r];
            }
    }
}

// ---------------- in-place row softmax on fp16 scores, row length 2048 ----------------
__global__ __launch_bounds__(256) void softmax_kernel(_Float16* __restrict__ S) {
    const long row = blockIdx.x;
    _Float16* p = S + row * 2048;
    half8 raw = ((const half8*)p)[threadIdx.x];
    float v[8];
#pragma unroll
    for (int i = 0; i < 8; i++) v[i] = (float)raw[i];

    float mx = v[0];
#pragma unroll
    for (int i = 1; i < 8; i++) mx = fmaxf(mx, v[i]);
#pragma unroll
    for (int off = 32; off > 0; off >>= 1) mx = fmaxf(mx, __shfl_xor(mx, off, 64));
    __shared__ float redm[4], reds[4];
    int lane = threadIdx.x & 63, w = threadIdx.x >> 6;
    if (lane == 0) redm[w] = mx;
    __syncthreads();
    mx = fmaxf(fmaxf(redm[0], redm[1]), fmaxf(redm[2], redm[3]));

    float e[8], sum = 0.f;
#pragma unroll
    for (int i = 0; i < 8; i++) { e[i] = __expf(v[i] - mx); sum += e[i]; }
#pragma unroll
    for (int off = 32; off > 0; off >>= 1) sum += __shfl_xor(sum, off, 64);
    if (lane == 0) reds[w] = sum;
    __syncthreads();
    sum = reds[0] + reds[1] + reds[2] + reds[3];
    float inv = 1.0f / sum;

    half8 o;
#pragma unroll
    for (int i = 0; i < 8; i++) o[i] = (_Float16)(e[i] * inv);
    ((half8*)p)[threadIdx.x] = o;
}

extern "C" void kernel_launch(void* const* d_in, const int* in_sizes, int n_in,
                              void* d_out, int out_size, void* d_ws, size_t ws_size,
                              hipStream_t stream) {
    const float* H  = (const float*)d_in[0];
    const float* E  = (const float*)d_in[1];
    const float* Wq = (const float*)d_in[2];
    const float* bq = (const float*)d_in[3];
    const float* Wk = (const float*)d_in[4];
    const float* bk = (const float*)d_in[5];
    const float* Wv = (const float*)d_in[6];
    const float* bv = (const float*)d_in[7];
    float* out = (float*)d_out;

    char* ws = (char*)d_ws;
    _Float16* Hh  = (_Float16*)(ws + 0L);
    _Float16* Eh  = (_Float16*)(ws + 33554432L);
    _Float16* WqT = (_Float16*)(ws + 67108864L);
    _Float16* WkT = (_Float16*)(ws + 69206016L);
    _Float16* WvT = (_Float16*)(ws + 71303168L);
    _Float16* Qh  = (_Float16*)(ws + 73400320L);
    _Float16* Kh  = (_Float16*)(ws + 106954752L);
    _Float16* Vt  = (_Float16*)(ws + 140509184L);
    _Float16* S   = (_Float16*)(ws + 174063616L);  // ends at 241172480

    // 1) fp32 -> fp16 activations (both tensors, one dispatch)
    cvt2_kernel<<<dim3(2048, 1, 2), 256, 0, stream>>>(H, E, Hh, Eh, 16384 * 1024 / 4);
    // 2) weight transpose+convert
    wtrans_kernel<<<dim3(32, 32, 3), 256, 0, stream>>>(Wq, Wk, Wv, WqT, WkT, WvT);
    // 3) merged QKV projections: M=16384, N=1024, K=1024 (1-D swizzled grid)
    QkvParams qp{Hh, Eh, WqT, WkT, WvT, bq, bk, bv, Qh, Kh, Vt};
    qkv_kernel<<<3072, 256, 0, stream>>>(qp);
    // 4) S = Q K^T * 0.125  (batched, M=N=2048, K=1024; batch z -> XCD z)
    gemm_bt<0, 4><<<2048, 256, 0, stream>>>(Qh, 2048L * 1024, 1024, Kh, 2048L * 1024, 1024,
                                            (void*)S, 2048L * 2048, 2048, 0.125f, 1024);
    // 5) in-place softmax over rows
    softmax_kernel<<<16384, 256, 0, stream>>>(S);
    // 6) O = P V  (batched, M=2048, N=1024, K=2048), fp32 out
    gemm_bt<1, 3><<<1024, 256, 0, stream>>>(S, 2048L * 2048, 2048, Vt, 1024L * 2048, 2048,
                                            (void*)out, 2048L * 1024, 1024, 1.f, 2048);
    (void)in_sizes; (void)n_in; (void)out_size; (void)ws_size;
}

// Round 5
// 451.816 us; speedup vs baseline: 1.4627x; 1.0664x over previous
//
#include <hip/hip_runtime.h>

typedef _Float16 half8 __attribute__((ext_vector_type(8)));
typedef _Float16 half4 __attribute__((ext_vector_type(4)));
typedef float f32x4 __attribute__((ext_vector_type(4)));

#define AS1 __attribute__((address_space(1)))
#define AS3 __attribute__((address_space(3)))

// ---------------- fp32 -> fp16 bulk convert (H and E in one dispatch) ----------------
__global__ __launch_bounds__(256) void cvt2_kernel(const float* __restrict__ H, const float* __restrict__ E,
                                                   _Float16* __restrict__ Hh, _Float16* __restrict__ Eh, int n4) {
    const float4* s4 = (const float4*)(blockIdx.z ? E : H);
    half4* d4 = (half4*)(blockIdx.z ? Eh : Hh);
    int i = blockIdx.x * blockDim.x + threadIdx.x;
    int stride = gridDim.x * blockDim.x;
    for (; i < n4; i += stride) {
        float4 f = s4[i];
        half4 o;
        o.x = (_Float16)f.x; o.y = (_Float16)f.y; o.z = (_Float16)f.z; o.w = (_Float16)f.w;
        d4[i] = o;
    }
}

// ---------------- weight transpose + convert: W[1024][1024] f32 -> Wt[n][k] fp16 ----------------
__global__ __launch_bounds__(256) void wtrans_kernel(const float* __restrict__ W0, const float* __restrict__ W1,
                                                     const float* __restrict__ W2,
                                                     _Float16* __restrict__ T0, _Float16* __restrict__ T1,
                                                     _Float16* __restrict__ T2) {
    const float* W = blockIdx.z == 0 ? W0 : (blockIdx.z == 1 ? W1 : W2);
    _Float16* T = blockIdx.z == 0 ? T0 : (blockIdx.z == 1 ? T1 : T2);
    __shared__ float tile[32][33];
    int tx = threadIdx.x & 31, tg = threadIdx.x >> 5;  // tg 0..7
    int k0 = blockIdx.y * 32, n0 = blockIdx.x * 32;
#pragma unroll
    for (int i = 0; i < 4; i++) tile[tg + i * 8][tx] = W[(long)(k0 + tg + i * 8) * 1024 + n0 + tx];
    __syncthreads();
#pragma unroll
    for (int i = 0; i < 4; i++) T[(long)(n0 + tg + i * 8) * 1024 + k0 + tx] = (_Float16)tile[tx][tg + i * 8];
}

// ---------------- shared GEMM core, BK=64: acc += A[128][K] * Bt[128][K]^T ----------------
// LDS tile: 128 rows x 64 k (128 B/row, eight 16-B chunks). Physical chunk = logical ^ (row&7).
// Staging: lane l covers row (l>>3), chunk (l&7) of each 8-row group -> each 8-lane group reads
// one contiguous 128-B row (coalesced). Fragment reads: 16 lanes hit 8 bank-groups x 2 = free.
// 32 MFMA per barrier pair (2x the BK=32 ratio) to amortize the vmcnt(0) barrier drain.
__device__ __forceinline__ void gemm_core(const _Float16* __restrict__ Ab, int lda,
                                          const _Float16* __restrict__ Bb, int ldb, int K,
                                          _Float16* sA, _Float16* sB, f32x4 acc[4][4]) {
    const int tid = threadIdx.x;
    const int wv = tid >> 6, lane = tid & 63;
    const int wr = wv >> 1, wc = wv & 1;
    const int quad = lane >> 4, l16 = lane & 15;
    const int srow_g = lane >> 3;                      // 0..7: row within 8-row staging group
    const int sclog = ((lane & 7) ^ srow_g) * 8;       // swizzled logical-chunk element offset
    const int p0 = (quad ^ (l16 & 7)) * 8;             // fragment phys chunk, k-half 0 (elements)

    for (int k0 = 0; k0 < K; k0 += 64) {
#pragma unroll
        for (int i = 0; i < 4; i++) {
            int row = wv * 32 + i * 8;
            __builtin_amdgcn_global_load_lds((const AS1 void*)(Ab + (long)(row + srow_g) * lda + k0 + sclog),
                                             (AS3 void*)(&sA[row * 64]), 16, 0, 0);
            __builtin_amdgcn_global_load_lds((const AS1 void*)(Bb + (long)(row + srow_g) * ldb + k0 + sclog),
                                             (AS3 void*)(&sB[row * 64]), 16, 0, 0);
        }
        __syncthreads();
        half8 af[4][2], bf[4][2];
#pragma unroll
        for (int mi = 0; mi < 4; mi++) {
            int r = (wr * 64 + mi * 16 + l16) * 64;
            af[mi][0] = *(const half8*)&sA[r + p0];
            af[mi][1] = *(const half8*)&sA[r + (p0 ^ 32)];   // phys ^ 4 chunks = ^32 elements
        }
#pragma unroll
        for (int ni = 0; ni < 4; ni++) {
            int r = (wc * 64 + ni * 16 + l16) * 64;
            bf[ni][0] = *(const half8*)&sB[r + p0];
            bf[ni][1] = *(const half8*)&sB[r + (p0 ^ 32)];
        }
#pragma unroll
        for (int mi = 0; mi < 4; mi++)
#pragma unroll
            for (int ni = 0; ni < 4; ni++) {
                acc[mi][ni] = __builtin_amdgcn_mfma_f32_16x16x32_f16(af[mi][0], bf[ni][0], acc[mi][ni], 0, 0, 0);
                acc[mi][ni] = __builtin_amdgcn_mfma_f32_16x16x32_f16(af[mi][1], bf[ni][1], acc[mi][ni], 0, 0, 0);
            }
        __syncthreads();
    }
}

// ---------------- merged QKV projection: 1-D grid 3072, XCD-swizzled (by%8 == xcd) ----------------
struct QkvParams {
    const _Float16 *Hh, *Eh, *WqT, *WkT, *WvT;
    const float *bq, *bk, *bv;
    _Float16 *Qh, *Kh, *Vt;
};

__global__ __launch_bounds__(256, 3) void qkv_kernel(QkvParams p) {
    __shared__ __align__(16) _Float16 sA[128 * 64];
    __shared__ __align__(16) _Float16 sB[128 * 64];
    const int b = blockIdx.x;             // 0..3071
    const int xcd = b & 7, s = b >> 3;    // s: 0..383
    const int z = s >> 7;                 // 0..2
    const int r = s & 127;
    const int by = xcd + ((r >> 3) << 3); // 0..127, by%8 == xcd
    const int bx = r & 7;                 // 0..7

    const _Float16* A  = (z == 0) ? p.Hh : p.Eh;
    const _Float16* Bt = (z == 0) ? p.WqT : (z == 1 ? p.WkT : p.WvT);
    const float* bias  = (z == 0) ? p.bq : (z == 1 ? p.bk : p.bv);
    const _Float16* Ab = A + (long)(by * 128) * 1024;
    const _Float16* Bb = Bt + (long)(bx * 128) * 1024;

    f32x4 acc[4][4];
#pragma unroll
    for (int i = 0; i < 4; i++)
#pragma unroll
        for (int j = 0; j < 4; j++) acc[i][j] = {0.f, 0.f, 0.f, 0.f};
    gemm_core(Ab, 1024, Bb, 1024, 1024, sA, sB, acc);

    const int wv = threadIdx.x >> 6, lane = threadIdx.x & 63;
    const int wr = wv >> 1, wc = wv & 1;
    const int quad = lane >> 4, l16 = lane & 15;
    const int m_base = by * 128 + wr * 64 + quad * 4;
    const int n_base = bx * 128 + wc * 64 + l16;

    if (z < 2) {
        _Float16* C = (z == 0) ? p.Qh : p.Kh;
#pragma unroll
        for (int mi = 0; mi < 4; mi++)
#pragma unroll
            for (int ni = 0; ni < 4; ni++) {
                int n = n_base + ni * 16;
                float bv_ = bias[n];
#pragma unroll
                for (int r2 = 0; r2 < 4; r2++)
                    C[(long)(m_base + mi * 16 + r2) * 1024 + n] = (_Float16)(acc[mi][ni][r2] + bv_);
            }
    } else {  // V: store transposed per batch: Vt[b][n][t]
        _Float16* C = p.Vt;
#pragma unroll
        for (int mi = 0; mi < 4; mi++) {
            int m0 = m_base + mi * 16;
            long bb = m0 >> 11;
            int t = m0 & 2047;
#pragma unroll
            for (int ni = 0; ni < 4; ni++) {
                int n = n_base + ni * 16;
                float bv_ = bias[n];
                half4 o;
                o.x = (_Float16)(acc[mi][ni][0] + bv_);
                o.y = (_Float16)(acc[mi][ni][1] + bv_);
                o.z = (_Float16)(acc[mi][ni][2] + bv_);
                o.w = (_Float16)(acc[mi][ni][3] + bv_);
                *(half4*)&C[bb * (1024L * 2048) + (long)n * 2048 + t] = o;
            }
        }
    }
}

// ---------------- batched GEMM, 1-D grid, batch z pinned to XCD z ----------------
// OUTK 0 = fp16 store (*scale), 1 = f32 store. GXLOG = log2(#x-tiles).
template <int OUTK, int GXLOG>
__global__ __launch_bounds__(256, 3) void gemm_bt(const _Float16* __restrict__ A, long bsA, int lda,
                                                  const _Float16* __restrict__ Bt, long bsB, int ldb,
                                                  void* __restrict__ Cv, long bsC, int ldc,
                                                  float scale, int K) {
    __shared__ __align__(16) _Float16 sA[128 * 64];
    __shared__ __align__(16) _Float16 sB[128 * 64];
    const int b = blockIdx.x;
    const long zb = b & 7;                 // batch == XCD
    const int s = b >> 3;
    const int bx = s & ((1 << GXLOG) - 1);
    const int by = s >> GXLOG;

    const _Float16* Ab = A + zb * bsA + (long)(by * 128) * lda;
    const _Float16* Bb = Bt + zb * bsB + (long)(bx * 128) * ldb;

    f32x4 acc[4][4];
#pragma unroll
    for (int i = 0; i < 4; i++)
#pragma unroll
        for (int j = 0; j < 4; j++) acc[i][j] = {0.f, 0.f, 0.f, 0.f};
    gemm_core(Ab, lda, Bb, ldb, K, sA, sB, acc);

    const int wv = threadIdx.x >> 6, lane = threadIdx.x & 63;
    const int wr = wv >> 1, wc = wv & 1;
    const int quad = lane >> 4, l16 = lane & 15;
    const int m_base = by * 128 + wr * 64 + quad * 4;
    const int n_base = bx * 128 + wc * 64 + l16;

    if (OUTK == 0) {
        _Float16* C = (_Float16*)Cv + zb * bsC;
#pragma unroll
        for (int mi = 0; mi < 4; mi++)
#pragma unroll
            for (int ni = 0; ni < 4; ni++) {
                int n = n_base + ni * 16;
#pragma unroll
                for (int r = 0; r < 4; r++)
                    C[(long)(m_base + mi * 16 + r) * ldc + n] = (_Float16)(acc[mi][ni][r] * scale);
            }
    } else {
        float* C = (float*)Cv + zb * bsC;
#pragma unroll
        for (int mi = 0; mi < 4; mi++)
#pragma unroll
            for (int ni = 0; ni < 4; ni++) {
                int n = n_base + ni * 16;
#pragma unroll
                for (int r = 0; r < 4; r++)
                    C[(long)(m_base + mi * 16 + r) * ldc + n] = acc[mi][ni][r];
            }
    }
}

// ---------------- in-place row softmax on fp16 scores, row length 2048 ----------------
__global__ __launch_bounds__(256) void softmax_kernel(_Float16* __restrict__ S) {
    const long row = blockIdx.x;
    _Float16* p = S + row * 2048;
    half8 raw = ((const half8*)p)[threadIdx.x];
    float v[8];
#pragma unroll
    for (int i = 0; i < 8; i++) v[i] = (float)raw[i];

    float mx = v[0];
#pragma unroll
    for (int i = 1; i < 8; i++) mx = fmaxf(mx, v[i]);
#pragma unroll
    for (int off = 32; off > 0; off >>= 1) mx = fmaxf(mx, __shfl_xor(mx, off, 64));
    __shared__ float redm[4], reds[4];
    int lane = threadIdx.x & 63, w = threadIdx.x >> 6;
    if (lane == 0) redm[w] = mx;
    __syncthreads();
    mx = fmaxf(fmaxf(redm[0], redm[1]), fmaxf(redm[2], redm[3]));

    float e[8], sum = 0.f;
#pragma unroll
    for (int i = 0; i < 8; i++) { e[i] = __expf(v[i] - mx); sum += e[i]; }
#pragma unroll
    for (int off = 32; off > 0; off >>= 1) sum += __shfl_xor(sum, off, 64);
    if (lane == 0) reds[w] = sum;
    __syncthreads();
    sum = reds[0] + reds[1] + reds[2] + reds[3];
    float inv = 1.0f / sum;

    half8 o;
#pragma unroll
    for (int i = 0; i < 8; i++) o[i] = (_Float16)(e[i] * inv);
    ((half8*)p)[threadIdx.x] = o;
}

extern "C" void kernel_launch(void* const* d_in, const int* in_sizes, int n_in,
                              void* d_out, int out_size, void* d_ws, size_t ws_size,
                              hipStream_t stream) {
    const float* H  = (const float*)d_in[0];
    const float* E  = (const float*)d_in[1];
    const float* Wq = (const float*)d_in[2];
    const float* bq = (const float*)d_in[3];
    const float* Wk = (const float*)d_in[4];
    const float* bk = (const float*)d_in[5];
    const float* Wv = (const float*)d_in[6];
    const float* bv = (const float*)d_in[7];
    float* out = (float*)d_out;

    char* ws = (char*)d_ws;
    _Float16* Hh  = (_Float16*)(ws + 0L);
    _Float16* Eh  = (_Float16*)(ws + 33554432L);
    _Float16* WqT = (_Float16*)(ws + 67108864L);
    _Float16* WkT = (_Float16*)(ws + 69206016L);
    _Float16* WvT = (_Float16*)(ws + 71303168L);
    _Float16* Qh  = (_Float16*)(ws + 73400320L);
    _Float16* Kh  = (_Float16*)(ws + 106954752L);
    _Float16* Vt  = (_Float16*)(ws + 140509184L);
    _Float16* S   = (_Float16*)(ws + 174063616L);  // ends at 241172480

    // 1) fp32 -> fp16 activations (both tensors, one dispatch)
    cvt2_kernel<<<dim3(2048, 1, 2), 256, 0, stream>>>(H, E, Hh, Eh, 16384 * 1024 / 4);
    // 2) weight transpose+convert
    wtrans_kernel<<<dim3(32, 32, 3), 256, 0, stream>>>(Wq, Wk, Wv, WqT, WkT, WvT);
    // 3) merged QKV projections: M=16384, N=1024, K=1024 (1-D swizzled grid)
    QkvParams qp{Hh, Eh, WqT, WkT, WvT, bq, bk, bv, Qh, Kh, Vt};
    qkv_kernel<<<3072, 256, 0, stream>>>(qp);
    // 4) S = Q K^T * 0.125  (batched, M=N=2048, K=1024; batch z -> XCD z)
    gemm_bt<0, 4><<<2048, 256, 0, stream>>>(Qh, 2048L * 1024, 1024, Kh, 2048L * 1024, 1024,
                                            (void*)S, 2048L * 2048, 2048, 0.125f, 1024);
    // 5) in-place softmax over rows
    softmax_kernel<<<16384, 256, 0, stream>>>(S);
    // 6) O = P V  (batched, M=2048, N=1024, K=2048), fp32 out
    gemm_bt<1, 3><<<1024, 256, 0, stream>>>(S, 2048L * 2048, 2048, Vt, 1024L * 2048, 2048,
                                            (void*)out, 2048L * 1024, 1024, 1.f, 2048);
    (void)in_sizes; (void)n_in; (void)out_size; (void)ws_size;
}